// Round 8
// baseline (1249.623 us; speedup 1.0000x reference)
//
#include <hip/hip_runtime.h>
#include <math.h>

#define N_NODES 100000
#define N_EDGES 1600000
#define DIM     128
#define NPOOL0  50000
#define NPOOL1  25000
#define NGRAPH  64

typedef __attribute__((ext_vector_type(8))) short short8;
typedef __attribute__((ext_vector_type(4))) float f32x4;

__device__ __forceinline__ float lrelu(float v) { return v > 0.f ? v : 0.01f * v; }

// f32 -> bf16 round-to-nearest-even
__device__ __forceinline__ unsigned short f2bf(float f) {
    unsigned u = __float_as_uint(f);
    unsigned r = u + 0x7FFFu + ((u >> 16) & 1u);
    return (unsigned short)(r >> 16);
}

// float atomic max (monotone trick, -inf init; verified r1..r7)
__device__ __forceinline__ void atomicMaxF(float* addr, float val) {
    if (val >= 0.f) atomicMax((int*)addr, __float_as_int(val));
    else            atomicMin((unsigned int*)addr, __float_as_uint(val));
}

// ---------------- misc ----------------
__global__ __launch_bounds__(256) void fill_f32(float* __restrict__ p, int n, float v) {
    int i = blockIdx.x * 256 + threadIdx.x;
    if (i < n) p[i] = v;
}
__global__ __launch_bounds__(256) void conv_weights(
        const float* __restrict__ w0a, const float* __restrict__ w0b,
        const float* __restrict__ w2a, const float* __restrict__ w2b,
        unsigned short* __restrict__ o0a, unsigned short* __restrict__ o0b,
        unsigned short* __restrict__ o2a, unsigned short* __restrict__ o2b) {
    int i = blockIdx.x * 256 + threadIdx.x;   // 98304 total
    if (i < 16384) o0a[i] = f2bf(w0a[i]);
    else if (i < 32768) o0b[i - 16384] = f2bf(w0b[i - 16384]);
    else if (i < 65536) o2a[i - 32768] = f2bf(w2a[i - 32768]);
    else if (i < 98304) o2b[i - 65536] = f2bf(w2b[i - 65536]);
}

// ---------------- MFMA 2-layer MLP (unchanged from r5/r6, verified) ----------------
template<int KIN, int HID, bool BF16IN>
__global__ __launch_bounds__(256) void mlp_mfma(
        const void* __restrict__ Xv, int R,
        const unsigned short* __restrict__ W1, const float* __restrict__ B1,
        const float* __restrict__ G1, const float* __restrict__ BE1,
        const unsigned short* __restrict__ W2, const float* __restrict__ B2,
        unsigned short* __restrict__ Y)
{
    constexpr int XS_S = KIN + 8;
    constexpr int TS_S = HID + 8;
    __shared__ unsigned short xs[64 * XS_S];
    __shared__ unsigned short ts[64 * TS_S];

    const int tid = threadIdx.x;
    const int r0 = blockIdx.x * 64;

    {
        const int row = tid >> 2;
        const int c0 = (tid & 3) * 32;
        const int gr = r0 + row;
        if (BF16IN) {
            const unsigned short* X = (const unsigned short*)Xv;
            #pragma unroll
            for (int q = 0; q < 4; ++q) {
                short8 v = short8{0,0,0,0,0,0,0,0};
                if (gr < R) v = *(const short8*)&X[(size_t)gr * KIN + c0 + q * 8];
                *(short8*)&xs[row * XS_S + c0 + q * 8] = v;
            }
        } else {
            const float* X = (const float*)Xv;
            #pragma unroll
            for (int q = 0; q < 4; ++q) {
                short8 v = short8{0,0,0,0,0,0,0,0};
                if (gr < R) {
                    float4 a = *(const float4*)&X[(size_t)gr * KIN + c0 + q * 8];
                    float4 b = *(const float4*)&X[(size_t)gr * KIN + c0 + q * 8 + 4];
                    v[0] = (short)f2bf(a.x); v[1] = (short)f2bf(a.y);
                    v[2] = (short)f2bf(a.z); v[3] = (short)f2bf(a.w);
                    v[4] = (short)f2bf(b.x); v[5] = (short)f2bf(b.y);
                    v[6] = (short)f2bf(b.z); v[7] = (short)f2bf(b.w);
                }
                *(short8*)&xs[row * XS_S + c0 + q * 8] = v;
            }
        }
    }
    __syncthreads();

    const int wv = tid >> 6;
    const int lane = tid & 63;
    const int lr = lane & 15;
    const int lq = lane >> 4;
    const int arow = wv * 16 + lr;

    constexpr int NCG1 = HID / 16;
    constexpr int NK1 = KIN / 32;
    f32x4 acc1[NCG1] = {};
    for (int kc = 0; kc < NK1; ++kc) {
        short8 a = *(short8*)&xs[arow * XS_S + kc * 32 + lq * 8];
        #pragma unroll
        for (int cg = 0; cg < NCG1; ++cg) {
            short8 b = *(const short8*)&W1[(size_t)(cg * 16 + lr) * KIN + kc * 32 + lq * 8];
            acc1[cg] = __builtin_amdgcn_mfma_f32_16x16x32_bf16(a, b, acc1[cg], 0, 0, 0);
        }
    }
    #pragma unroll
    for (int cg = 0; cg < NCG1; ++cg) {
        const int c = cg * 16 + lr;
        const float bb = B1[c], gg = G1[c], ee = BE1[c];
        #pragma unroll
        for (int q = 0; q < 4; ++q) {
            const int rr = wv * 16 + lq * 4 + q;
            float v = (acc1[cg][q] + bb) * gg + ee;
            ts[rr * TS_S + c] = f2bf(lrelu(v));
        }
    }

    constexpr int NK2 = HID / 32;
    f32x4 acc2[8] = {};
    for (int kc = 0; kc < NK2; ++kc) {
        short8 a = *(short8*)&ts[arow * TS_S + kc * 32 + lq * 8];
        #pragma unroll
        for (int cg = 0; cg < 8; ++cg) {
            short8 b = *(const short8*)&W2[(size_t)(cg * 16 + lr) * HID + kc * 32 + lq * 8];
            acc2[cg] = __builtin_amdgcn_mfma_f32_16x16x32_bf16(a, b, acc2[cg], 0, 0, 0);
        }
    }
    #pragma unroll
    for (int cg = 0; cg < 8; ++cg) {
        const int c = cg * 16 + lr;
        const float bb = B2[c];
        #pragma unroll
        for (int q = 0; q < 4; ++q) {
            const int gr = r0 + wv * 16 + lq * 4 + q;
            if (gr < R) Y[(size_t)gr * 128 + c] = f2bf(acc2[cg][q] + bb);
        }
    }
}

// ============ atomic-free CSR build: MSD bucket decomposition ============
// Pass A1: per-block coarse histogram (key>>SHIFT), plain stores, bin-major table
template<int SHIFT>
__global__ __launch_bounds__(256) void hist_coarse(const int* __restrict__ key,
                                                   int* __restrict__ bh, int E, int nbkt) {
    __shared__ int h[256];
    const int t = threadIdx.x;
    h[t] = 0;
    __syncthreads();
    const int base = blockIdx.x * 16384;
    const int end = min(base + 16384, E);
    for (int e = base + t; e < end; e += 256) atomicAdd(&h[key[e] >> SHIFT], 1);
    __syncthreads();
    if (t < nbkt) bh[t * gridDim.x + blockIdx.x] = h[t];
}
// Pass A2: single block: per-bin scan across blocks + exclusive scan over bins
__global__ __launch_bounds__(256) void scan_coarse(int* __restrict__ bh, int* __restrict__ bbase,
                                                   int nblk, int nbkt, int E) {
    __shared__ int sc[256], tot[256];
    const int t = threadIdx.x;
    int sum = 0;
    if (t < nbkt) {
        for (int b = 0; b < nblk; ++b) { int v = bh[t * nblk + b]; bh[t * nblk + b] = sum; sum += v; }
    }
    tot[t] = sum;
    sc[t] = sum;
    __syncthreads();
    #pragma unroll
    for (int d = 1; d < 256; d <<= 1) {
        int v = (t >= d) ? sc[t - d] : 0;
        __syncthreads();
        sc[t] += v;
        __syncthreads();
    }
    const int base = sc[t] - tot[t];   // exclusive
    if (t < nbkt) {
        for (int b = 0; b < nblk; ++b) bh[t * nblk + b] += base;
        bbase[t] = base;
    }
    if (t == nbkt) bbase[t] = E;
}
// Pass A3: scatter into coarse buckets (LDS rank; plain global stores)
template<int SHIFT, bool PAY>
__global__ __launch_bounds__(256) void scatter_coarse(
        const int* __restrict__ key, const int* __restrict__ aux,
        const int* __restrict__ bh, int* __restrict__ keyT, int2* __restrict__ packT,
        int E, int nblk, int nbkt) {
    __shared__ int off[256];
    const int t = threadIdx.x;
    if (t < nbkt) off[t] = bh[t * nblk + blockIdx.x];
    __syncthreads();
    const int base = blockIdx.x * 16384;
    const int end = min(base + 16384, E);
    for (int e = base + t; e < end; e += 256) {
        const int k = key[e];
        const int pos = atomicAdd(&off[k >> SHIFT], 1);     // LDS atomic
        keyT[pos] = k;
        if (PAY) packT[pos] = make_int2(aux[e], e);
    }
}
// Pass B (hist-only): per-bucket exact histogram -> dis = rsqrt(1 + deg)
template<int SHIFT>
__global__ __launch_bounds__(1 << SHIFT) void hist_finalize(
        const int* __restrict__ keyT, const int* __restrict__ bbase,
        float* __restrict__ dis, int nnodes) {
    constexpr int NB = 1 << SHIFT;
    __shared__ int h[NB];
    const int t = threadIdx.x, bkt = blockIdx.x;
    const int b0 = bbase[bkt], b1 = bbase[bkt + 1];
    h[t] = 0;
    __syncthreads();
    for (int i = b0 + t; i < b1; i += NB) atomicAdd(&h[keyT[i] & (NB - 1)], 1);
    __syncthreads();
    const int node = bkt * NB + t;
    if (node < nnodes) dis[node] = rsqrtf(1.0f + (float)h[t]);
}
// Pass B (CSR): per-bucket exact hist + LDS scan -> offs/cnt (coalesced stores) + packed scatter
template<int SHIFT>
__global__ __launch_bounds__(1 << SHIFT) void bucket_finalize(
        const int* __restrict__ keyT, const int2* __restrict__ packT,
        const float* __restrict__ dis, const float* __restrict__ ea,
        const int* __restrict__ bbase,
        int* __restrict__ offsN, int* __restrict__ cntN, int2* __restrict__ pack, int nnodes) {
    constexpr int NB = 1 << SHIFT;
    __shared__ int h[NB], o[NB];
    const int t = threadIdx.x, bkt = blockIdx.x;
    const int b0 = bbase[bkt], b1 = bbase[bkt + 1];
    h[t] = 0;
    __syncthreads();
    for (int i = b0 + t; i < b1; i += NB) atomicAdd(&h[keyT[i] & (NB - 1)], 1);
    __syncthreads();
    o[t] = h[t];
    __syncthreads();
    #pragma unroll
    for (int d = 1; d < NB; d <<= 1) {
        int v = (t >= d) ? o[t - d] : 0;
        __syncthreads();
        o[t] += v;
        __syncthreads();
    }
    const int excl = o[t] - h[t];
    const int node = bkt * NB + t;
    if (node < nnodes) { offsN[node] = b0 + excl; cntN[node] = h[t]; }
    o[t] = excl;
    __syncthreads();
    for (int i = b0 + t; i < b1; i += NB) {
        const int k = keyT[i];
        const int2 p = packT[i];
        const int pos = b0 + atomicAdd(&o[k & (NB - 1)], 1);  // LDS atomic
        pack[pos] = make_int2(p.x, __float_as_int(dis[p.x] * ea[p.y]));
    }
}

// ---------------- small bookkeeping (low-contention atomics) ----------------
__global__ __launch_bounds__(256) void build_cmap(const int* __restrict__ c0, const int* __restrict__ c1,
                                                  int* __restrict__ cmap, int n) {
    int i = blockIdx.x * 256 + threadIdx.x;
    if (i < n) cmap[i] = c1[c0[i]];
}
__global__ __launch_bounds__(256) void edgemap(
        const int* __restrict__ ei0, const int* __restrict__ ei1,
        const int* __restrict__ cmap,
        int* __restrict__ src2, int* __restrict__ dst2, int E)
{
    int e = blockIdx.x * 256 + threadIdx.x;
    if (e < E) {
        src2[e] = cmap[ei0[e]];
        dst2[e] = cmap[ei1[e]];
    }
}
__global__ __launch_bounds__(256) void seg_count(const int* __restrict__ map, int* __restrict__ cnt, int n) {
    int i = blockIdx.x * 256 + threadIdx.x;
    if (i < n) atomicAdd(&cnt[map[i]], 1);
}
__global__ __launch_bounds__(256) void place_idx(const int* __restrict__ map, int* __restrict__ fill,
                                                 int* __restrict__ list, int n) {
    int i = blockIdx.x * 256 + threadIdx.x;
    if (i < n) {
        int pos = atomicAdd(&fill[map[i]], 1);
        list[pos] = i;
    }
}
__global__ __launch_bounds__(256) void segmax_i32(const int* __restrict__ map, const int* __restrict__ vals,
                                                  int* __restrict__ out, int n) {
    int i = blockIdx.x * 256 + threadIdx.x;
    if (i < n) atomicMax(&out[map[i]], vals[i]);
}
__global__ __launch_bounds__(256) void scan_blk(const int* __restrict__ cnt, int* __restrict__ offs,
                                                int* __restrict__ bsum, int n) {
    __shared__ int s[256];
    const int tid = threadIdx.x;
    const int i = blockIdx.x * 256 + tid;
    int v = (i < n) ? cnt[i] : 0;
    s[tid] = v;
    __syncthreads();
    #pragma unroll
    for (int d = 1; d < 256; d <<= 1) {
        int t = (tid >= d) ? s[tid - d] : 0;
        __syncthreads();
        s[tid] += t;
        __syncthreads();
    }
    if (i < n) offs[i] = s[tid] - v;
    if (tid == 255) bsum[blockIdx.x] = s[255];
}
__global__ __launch_bounds__(512) void scan_top(int* __restrict__ bsum, int nb) {
    __shared__ int s[512];
    const int tid = threadIdx.x;
    int v = (tid < nb) ? bsum[tid] : 0;
    s[tid] = v;
    __syncthreads();
    #pragma unroll
    for (int d = 1; d < 512; d <<= 1) {
        int t = (tid >= d) ? s[tid - d] : 0;
        __syncthreads();
        s[tid] += t;
        __syncthreads();
    }
    if (tid < nb) bsum[tid] = s[tid] - v;
}
__global__ __launch_bounds__(256) void scan_add(int* __restrict__ offs, const int* __restrict__ bsum,
                                                int* __restrict__ fill, int n) {
    int i = blockIdx.x * 256 + threadIdx.x;
    if (i < n) {
        int o = offs[i] + bsum[i >> 8];
        offs[i] = o;
        fill[i] = o;
    }
}

// ---------------- gather-reduce (one wave per dst node; packed CSR; readlane broadcast) ----------------
#define EDGE_ITER(K, A0, A1) {                                                  \
    int s_ = __builtin_amdgcn_readlane(pv.x, (K));                              \
    float w_ = __int_as_float(__builtin_amdgcn_readlane(pv.y, (K)));            \
    unsigned hv_ = hrows[(size_t)s_ * 64 + lane];                               \
    float c_ = w_ * di;                                                         \
    A0 += c_ * __uint_as_float(hv_ << 16);                                      \
    A1 += c_ * __uint_as_float(hv_ & 0xFFFF0000u); }

__global__ __launch_bounds__(256) void gather0(
        const unsigned short* __restrict__ h16, const float* __restrict__ x,
        const float* __restrict__ dis, const int* __restrict__ offs,
        const int* __restrict__ cnt, const int2* __restrict__ pack,
        unsigned* __restrict__ agg0)
{
    const int wid = (blockIdx.x * 256 + threadIdx.x) >> 6;
    if (wid >= N_NODES) return;
    const int lane = threadIdx.x & 63;
    const float di = dis[wid];
    const unsigned* hrows = (const unsigned*)h16;

    unsigned hself = hrows[(size_t)wid * 64 + lane];
    float a0 = di * di * __uint_as_float(hself << 16);
    float a1 = di * di * __uint_as_float(hself & 0xFFFF0000u);
    float b0 = 0.f, b1 = 0.f;

    const int base = offs[wid], n = cnt[wid];
    int k0 = 0;
    for (; k0 + 64 <= n; k0 += 64) {
        int2 pv = pack[base + k0 + lane];
        #pragma unroll
        for (int k = 0; k < 64; k += 2) {
            EDGE_ITER(k,     a0, a1);
            EDGE_ITER(k + 1, b0, b1);
        }
    }
    const int rem = n - k0;
    if (rem > 0) {
        int2 pv = (lane < rem) ? pack[base + k0 + lane] : make_int2(0, 0);
        #pragma unroll 4
        for (int k = 0; k < rem; ++k) EDGE_ITER(k, a0, a1);
    }
    a0 += b0; a1 += b1;

    float2 xv = *(const float2*)&x[(size_t)wid * DIM + lane * 2];
    agg0[(size_t)wid * 64 + lane] =
        ((unsigned)f2bf(a1 + xv.y) << 16) | (unsigned)f2bf(a0 + xv.x);
}

__global__ __launch_bounds__(256) void gather2(
        const unsigned short* __restrict__ hm2,
        const float* __restrict__ dis, const int* __restrict__ offs,
        const int* __restrict__ cnt, const int2* __restrict__ pack,
        float* __restrict__ agg2)
{
    const int wid = (blockIdx.x * 256 + threadIdx.x) >> 6;
    if (wid >= NPOOL1) return;
    const int lane = threadIdx.x & 63;
    const float di = dis[wid];
    const unsigned* hrows = (const unsigned*)hm2;

    unsigned hself = hrows[(size_t)wid * 64 + lane];
    float a0 = di * di * __uint_as_float(hself << 16);
    float a1 = di * di * __uint_as_float(hself & 0xFFFF0000u);
    float b0 = 0.f, b1 = 0.f;

    const int base = offs[wid], n = cnt[wid];
    int k0 = 0;
    for (; k0 + 64 <= n; k0 += 64) {
        int2 pv = pack[base + k0 + lane];
        #pragma unroll
        for (int k = 0; k < 64; k += 2) {
            EDGE_ITER(k,     a0, a1);
            EDGE_ITER(k + 1, b0, b1);
        }
    }
    const int rem = n - k0;
    if (rem > 0) {
        int2 pv = (lane < rem) ? pack[base + k0 + lane] : make_int2(0, 0);
        #pragma unroll 4
        for (int k = 0; k < rem; ++k) EDGE_ITER(k, a0, a1);
    }
    a0 += b0; a1 += b1;

    float2 o = make_float2(lrelu(a0), lrelu(a1));
    *(float2*)&agg2[(size_t)wid * DIM + lane * 2] = o;
}

// ---------------- pool gathers (atomic-free segment max via member lists) ----------------
__global__ __launch_bounds__(256) void pool1_gather(
        const unsigned* __restrict__ agg0, const float* __restrict__ x,
        const int* __restrict__ offsc, const int* __restrict__ cntc,
        const int* __restrict__ listc, unsigned* __restrict__ h2)
{
    const int c = (blockIdx.x * 256 + threadIdx.x) >> 6;
    if (c >= NPOOL0) return;
    const int lane = threadIdx.x & 63;
    const int base = offsc[c], n = cntc[c];
    float p0 = -INFINITY, p1 = -INFINITY, o0 = -INFINITY, o1 = -INFINITY;
    for (int k = 0; k < n; ++k) {
        const int node = listc[base + k];
        const unsigned hv = agg0[(size_t)node * 64 + lane];
        const float2 xv = *(const float2*)&x[(size_t)node * 128 + lane * 2];
        p0 = fmaxf(p0, lrelu(__uint_as_float(hv << 16)));
        p1 = fmaxf(p1, lrelu(__uint_as_float(hv & 0xFFFF0000u)));
        o0 = fmaxf(o0, xv.x);
        o1 = fmaxf(o1, xv.y);
    }
    p0 = (p0 == -INFINITY) ? 0.f : p0;
    p1 = (p1 == -INFINITY) ? 0.f : p1;
    o0 = (o0 == -INFINITY) ? 0.f : o0;
    o1 = (o1 == -INFINITY) ? 0.f : o1;
    h2[(size_t)c * 64 + lane] =
        ((unsigned)f2bf(p1 + o1) << 16) | (unsigned)f2bf(p0 + o0);
}

__global__ __launch_bounds__(256) void pool2_gather(
        const unsigned* __restrict__ h2,
        const int* __restrict__ offsd, const int* __restrict__ cntd,
        const int* __restrict__ listd, unsigned* __restrict__ x2)
{
    const int d = (blockIdx.x * 256 + threadIdx.x) >> 6;
    if (d >= NPOOL1) return;
    const int lane = threadIdx.x & 63;
    const int base = offsd[d], n = cntd[d];
    float m0 = -INFINITY, m1 = -INFINITY;
    for (int k = 0; k < n; ++k) {
        const int node = listd[base + k];
        const unsigned hv = h2[(size_t)node * 64 + lane];
        m0 = fmaxf(m0, lrelu(__uint_as_float(hv << 16)));
        m1 = fmaxf(m1, lrelu(__uint_as_float(hv & 0xFFFF0000u)));
    }
    m0 = (m0 == -INFINITY) ? 0.f : m0;
    m1 = (m1 == -INFINITY) ? 0.f : m1;
    x2[(size_t)d * 64 + lane] = ((unsigned)f2bf(m1) << 16) | (unsigned)f2bf(m0);
}

// ---------------- parallel global max pool ----------------
__global__ __launch_bounds__(256) void gpool_scan(
        const float* __restrict__ agg2, const int* __restrict__ listg,
        const int* __restrict__ pb2, float* __restrict__ gmax)
{
    const int wave = (blockIdx.x * 256 + threadIdx.x) >> 6;   // 0..511
    const int lane = threadIdx.x & 63;
    const int CH = (NPOOL1 + 511) / 512;                      // 49
    const int p0 = wave * CH;
    const int p1 = min(p0 + CH, NPOOL1);
    if (p0 >= NPOOL1) return;

    float m0 = -INFINITY, m1 = -INFINITY;
    int cur = -1;
    for (int p = p0; p < p1; ++p) {
        const int node = listg[p];
        const int g = pb2[node];
        if (g != cur) {
            if (cur >= 0) {
                float* gp = &gmax[(size_t)cur * DIM + lane * 2];
                atomicMaxF(gp + 0, m0);
                atomicMaxF(gp + 1, m1);
            }
            cur = g; m0 = -INFINITY; m1 = -INFINITY;
        }
        const float2 v = *(const float2*)&agg2[(size_t)node * DIM + lane * 2];
        m0 = fmaxf(m0, v.x);
        m1 = fmaxf(m1, v.y);
    }
    float* gp = &gmax[(size_t)cur * DIM + lane * 2];
    atomicMaxF(gp + 0, m0);
    atomicMaxF(gp + 1, m1);
}

// ---------------- head ----------------
__global__ __launch_bounds__(128) void head(
        const float* __restrict__ gmax, const float* __restrict__ energy,
        const float* __restrict__ emb_w, const float* __restrict__ emb_b,
        const float* __restrict__ emb_g, const float* __restrict__ emb_be,
        const float* __restrict__ lw1, const float* __restrict__ lb1,
        const float* __restrict__ lg, const float* __restrict__ lbe,
        const float* __restrict__ lw2, const float* __restrict__ lb2,
        float* __restrict__ out)
{
    const int g = blockIdx.x;
    const int t = threadIdx.x;
    __shared__ float z[136];
    __shared__ float red[128];

    {
        float v = gmax[(size_t)g * DIM + t];
        z[t] = (v == -INFINITY) ? 0.f : v;
    }
    if (t < 8) {
        float s = 0.f;
        #pragma unroll
        for (int k = 0; k < 21; ++k) s += energy[g * 21 + k] * emb_w[t * 21 + k];
        s = (s + emb_b[t]) * emb_g[t] + emb_be[t];
        z[128 + t] = lrelu(s);
    }
    __syncthreads();
    float s = 0.f;
    #pragma unroll 8
    for (int k = 0; k < 136; ++k) s += z[k] * lw1[t * 136 + k];
    float z2 = lrelu((s + lb1[t]) * lg[t] + lbe[t]);
    red[t] = z2 * lw2[t];
    __syncthreads();
    if (t == 0) {
        float acc = lb2[0];
        for (int k = 0; k < 128; ++k) acc += red[k];
        out[g] = acc;
    }
}

extern "C" void kernel_launch(void* const* d_in, const int* in_sizes, int n_in,
                              void* d_out, int out_size, void* d_ws, size_t ws_size,
                              hipStream_t stream) {
    const float* x        = (const float*)d_in[0];
    const float* edge_attr= (const float*)d_in[1];
    const float* energy   = (const float*)d_in[2];
    const float* w0a = (const float*)d_in[3];
    const float* b0a = (const float*)d_in[4];
    const float* g0  = (const float*)d_in[5];
    const float* be0 = (const float*)d_in[6];
    const float* w0b = (const float*)d_in[7];
    const float* b0b = (const float*)d_in[8];
    const float* w2a = (const float*)d_in[15];
    const float* b2a = (const float*)d_in[16];
    const float* g2  = (const float*)d_in[17];
    const float* be2 = (const float*)d_in[18];
    const float* w2b = (const float*)d_in[19];
    const float* b2b = (const float*)d_in[20];
    const float* emb_w  = (const float*)d_in[21];
    const float* emb_b  = (const float*)d_in[22];
    const float* emb_g  = (const float*)d_in[23];
    const float* emb_be = (const float*)d_in[24];
    const float* lw1 = (const float*)d_in[25];
    const float* lb1 = (const float*)d_in[26];
    const float* lg  = (const float*)d_in[27];
    const float* lbe = (const float*)d_in[28];
    const float* lw2 = (const float*)d_in[29];
    const float* lb2 = (const float*)d_in[30];
    const int* ei0   = (const int*)d_in[31];
    const int* ei1   = ei0 + N_EDGES;
    const int* batch = (const int*)d_in[32];
    const int* c0    = (const int*)d_in[33];
    const int* c1    = (const int*)d_in[34];
    float* out = (float*)d_out;

    // ---- workspace layout (peak ~87.4 MB) ----
    char* ws = (char*)d_ws;
    unsigned short* h16 = (unsigned short*)(ws + 0);         // [N,128] bf16 (dead after gather0)
    int*   src2  = (int*)(ws + 0);                           // [E] (alias h16, after gather0)
    int*   dst2  = (int*)(ws + 6400000);                     // [E]
    float* agg2  = (float*)(ws + 12800000);                  // [N1,128] f32
    unsigned* agg0 = (unsigned*)(ws + 25600000);             // [N,128] bf16 (dead after pool1_gather)
    unsigned short* hm2 = (unsigned short*)(ws + 25600000);  // alias agg0
    int2*  pack  = (int2*)(ws + 51200000);                   // [E] final CSR payload (both levels)
    unsigned* h2 = (unsigned*)(ws + 64000000);               // [N0,128] bf16; also packT scratch
    int2*  packT = (int2*)(ws + 64000000);                   // alias h2 (used before h2 is written / after dead)
    unsigned* x2 = (unsigned*)(ws + 76800000);               // [N1,128] bf16; also keyT scratch
    int*   keyT  = (int*)(ws + 76800000);                    // alias x2 (used before x2 written / after dead)
    float* dis0  = (float*)(ws + 83200000);                  // [N]
    float* dis2  = (float*)(ws + 83600000);                  // [N1]
    // zero region (single memset)
    char*  zbase = ws + 83700000;
    int*   cntc  = (int*)(ws + 83700000);                    // [N0]
    int*   cntd  = (int*)(ws + 83900000);                    // [N1]
    int*   cntg  = (int*)(ws + 84000000);                    // [64]
    int*   pb    = (int*)(ws + 84000256);                    // [N0]
    int*   pb2   = (int*)(ws + 84200256);                    // [N1]
    const size_t ZBYTES = 84300256 - 83700000;
    int*   offsc = (int*)(ws + 84300256);
    int*   fillc = (int*)(ws + 84500256);
    int*   listc = (int*)(ws + 84700256);                    // [N]
    int*   offsd = (int*)(ws + 85100256);
    int*   filld = (int*)(ws + 85200256);
    int*   listd = (int*)(ws + 85300256);                    // [N0]
    int*   offsg = (int*)(ws + 85500256);
    int*   fillg = (int*)(ws + 85500512);
    int*   listg = (int*)(ws + 85500768);                    // [N1]
    int*   bsum  = (int*)(ws + 85600768);                    // [<=512]
    int*   cmap  = (int*)(ws + 85602816);                    // [N]
    int*   offs0 = (int*)(ws + 86002816);                    // [N]
    int*   cnt0  = (int*)(ws + 86402816);                    // [N]
    int*   offs2 = (int*)(ws + 86802816);                    // [N1]
    int*   cnt2  = (int*)(ws + 86902816);                    // [N1]
    unsigned short* w0a16 = (unsigned short*)(ws + 87002816);
    unsigned short* w0b16 = (unsigned short*)(ws + 87035584);
    unsigned short* w2a16 = (unsigned short*)(ws + 87068352);
    unsigned short* w2b16 = (unsigned short*)(ws + 87133888);
    float* gmax  = (float*)(ws + 87199424);                  // [64,128]
    int*   bh    = (int*)(ws + 87232192);                    // blockhist [256*98]
    int*   bbase = (int*)(ws + 87332544);                    // [197]

    (void)in_sizes; (void)n_in; (void)out_size; (void)ws_size;

    const int NB0 = (N_NODES + 255) / 256;   // 391
    const int NBC = (NPOOL0 + 255) / 256;    // 196
    const int NB1 = (NPOOL1 + 255) / 256;    // 98
    const int NBE = (N_EDGES + 255) / 256;
    const int NBLK = (N_EDGES + 16383) / 16384;  // 98
    const int NBKT0 = (N_NODES + 511) / 512;     // 196
    const int NBKT2 = (NPOOL1 + 127) / 128;      // 196

    // ---- init ----
    hipMemsetAsync(zbase, 0, ZBYTES, stream);
    fill_f32<<<32, 256, 0, stream>>>(gmax, NGRAPH * DIM, -INFINITY);
    conv_weights<<<384, 256, 0, stream>>>(w0a, w0b, w2a, w2b, w0a16, w0b16, w2a16, w2b16);

    // ---- mpnn0 MLP ----
    mlp_mfma<128, 128, false><<<(N_NODES + 63) / 64, 256, 0, stream>>>(
        x, N_NODES, w0a16, b0a, g0, be0, w0b16, b0b, h16);

    // ---- level-0 out-degree histogram (atomic-free) -> dis0 ----
    hist_coarse<9><<<NBLK, 256, 0, stream>>>(ei0, bh, N_EDGES, NBKT0);
    scan_coarse<<<1, 256, 0, stream>>>(bh, bbase, NBLK, NBKT0, N_EDGES);
    scatter_coarse<9, false><<<NBLK, 256, 0, stream>>>(ei0, nullptr, bh, keyT, nullptr, N_EDGES, NBLK, NBKT0);
    hist_finalize<9><<<NBKT0, 512, 0, stream>>>(keyT, bbase, dis0, N_NODES);

    // ---- level-0 dst-CSR (atomic-free) ----
    hist_coarse<9><<<NBLK, 256, 0, stream>>>(ei1, bh, N_EDGES, NBKT0);
    scan_coarse<<<1, 256, 0, stream>>>(bh, bbase, NBLK, NBKT0, N_EDGES);
    scatter_coarse<9, true><<<NBLK, 256, 0, stream>>>(ei1, ei0, bh, keyT, packT, N_EDGES, NBLK, NBKT0);
    bucket_finalize<9><<<NBKT0, 512, 0, stream>>>(keyT, packT, dis0, edge_attr, bbase, offs0, cnt0, pack, N_NODES);
    gather0<<<(N_NODES * 64) / 256, 256, 0, stream>>>(h16, x, dis0, offs0, cnt0, pack, agg0);

    // ---- pool1 ----
    seg_count<<<NB0, 256, 0, stream>>>(c0, cntc, N_NODES);
    scan_blk<<<NBC, 256, 0, stream>>>(cntc, offsc, bsum, NPOOL0);
    scan_top<<<1, 512, 0, stream>>>(bsum, NBC);
    scan_add<<<NBC, 256, 0, stream>>>(offsc, bsum, fillc, NPOOL0);
    place_idx<<<NB0, 256, 0, stream>>>(c0, fillc, listc, N_NODES);
    segmax_i32<<<NB0, 256, 0, stream>>>(c0, batch, pb, N_NODES);
    pool1_gather<<<(NPOOL0 * 64) / 256, 256, 0, stream>>>(agg0, x, offsc, cntc, listc, h2);

    // ---- pool2 ----
    seg_count<<<NBC, 256, 0, stream>>>(c1, cntd, NPOOL0);
    scan_blk<<<NB1, 256, 0, stream>>>(cntd, offsd, bsum, NPOOL1);
    scan_top<<<1, 512, 0, stream>>>(bsum, NB1);
    scan_add<<<NB1, 256, 0, stream>>>(offsd, bsum, filld, NPOOL1);
    place_idx<<<NBC, 256, 0, stream>>>(c1, filld, listd, NPOOL0);
    segmax_i32<<<NBC, 256, 0, stream>>>(c1, pb, pb2, NPOOL0);
    pool2_gather<<<(NPOOL1 * 64) / 256, 256, 0, stream>>>(h2, offsd, cntd, listd, x2);

    // ---- mpnn2: remap + MLP ----
    build_cmap<<<NB0, 256, 0, stream>>>(c0, c1, cmap, N_NODES);
    edgemap<<<NBE, 256, 0, stream>>>(ei0, ei1, cmap, src2, dst2, N_EDGES);
    mlp_mfma<128, 256, true><<<(NPOOL1 + 63) / 64, 256, 0, stream>>>(
        x2, NPOOL1, w2a16, b2a, g2, be2, w2b16, b2b, hm2);
    // (x2, h2 now dead -> keyT/packT scratch reusable)

    // ---- level-2 out-degree histogram -> dis2 ----
    hist_coarse<7><<<NBLK, 256, 0, stream>>>(src2, bh, N_EDGES, NBKT2);
    scan_coarse<<<1, 256, 0, stream>>>(bh, bbase, NBLK, NBKT2, N_EDGES);
    scatter_coarse<7, false><<<NBLK, 256, 0, stream>>>(src2, nullptr, bh, keyT, nullptr, N_EDGES, NBLK, NBKT2);
    hist_finalize<7><<<NBKT2, 128, 0, stream>>>(keyT, bbase, dis2, NPOOL1);

    // ---- level-2 dst-CSR ----
    hist_coarse<7><<<NBLK, 256, 0, stream>>>(dst2, bh, N_EDGES, NBKT2);
    scan_coarse<<<1, 256, 0, stream>>>(bh, bbase, NBLK, NBKT2, N_EDGES);
    scatter_coarse<7, true><<<NBLK, 256, 0, stream>>>(dst2, src2, bh, keyT, packT, N_EDGES, NBLK, NBKT2);
    bucket_finalize<7><<<NBKT2, 128, 0, stream>>>(keyT, packT, dis2, edge_attr, bbase, offs2, cnt2, pack, NPOOL1);
    gather2<<<(NPOOL1 * 64) / 256, 256, 0, stream>>>(hm2, dis2, offs2, cnt2, pack, agg2);

    // ---- graph buckets + parallel gpool + head ----
    seg_count<<<NB1, 256, 0, stream>>>(pb2, cntg, NPOOL1);
    scan_blk<<<1, 256, 0, stream>>>(cntg, offsg, bsum, NGRAPH);
    scan_top<<<1, 512, 0, stream>>>(bsum, 1);
    scan_add<<<1, 256, 0, stream>>>(offsg, bsum, fillg, NGRAPH);
    place_idx<<<NB1, 256, 0, stream>>>(pb2, fillg, listg, NPOOL1);
    gpool_scan<<<128, 256, 0, stream>>>(agg2, listg, pb2, gmax);
    head<<<NGRAPH, 128, 0, stream>>>(gmax, energy, emb_w, emb_b, emb_g, emb_be,
                                     lw1, lb1, lg, lbe, lw2, lb2, out);
}